// Round 4
// baseline (304.477 us; speedup 1.0000x reference)
//
#include <hip/hip_runtime.h>

#define B_ 32
#define C_ 64
#define N_ 2048
#define H_ 128

typedef unsigned short u16;
typedef unsigned int u32;
typedef float f32x4 __attribute__((ext_vector_type(4)));
typedef __bf16 bf16x8 __attribute__((ext_vector_type(8)));
typedef __bf16 bf16x4 __attribute__((ext_vector_type(4)));
typedef unsigned short u16x4 __attribute__((ext_vector_type(4)));

#define MFMA(a, b, c) __builtin_amdgcn_mfma_f32_16x16x32_bf16(a, b, c, 0, 0, 0)
#define LOG2E 1.44269504088896f

// XOR swizzle for 128-byte-stride LDS rows (bf16 [*][64]); returns BYTE offset.
__device__ __forceinline__ int swz(int row, int cb) { return row * 128 + (cb ^ ((row & 7) << 4)); }
// same for 256-byte-stride rows (bf16 [*][128])
__device__ __forceinline__ int swz256(int row, int cb) { return row * 256 + (cb ^ ((row & 7) << 4)); }

__device__ __forceinline__ bf16x8 cvt8(const float* p, float s) {
    f32x4 a = *(const f32x4*)p, b = *(const f32x4*)(p + 4);
    bf16x8 o;
    o[0] = (__bf16)(a[0] * s); o[1] = (__bf16)(a[1] * s);
    o[2] = (__bf16)(a[2] * s); o[3] = (__bf16)(a[3] * s);
    o[4] = (__bf16)(b[0] * s); o[5] = (__bf16)(b[1] * s);
    o[6] = (__bf16)(b[2] * s); o[7] = (__bf16)(b[3] * s);
    return o;
}

// ---------------------------------------------------------------------------
// Kernel 1: Q = (0.125*log2e)*wq*x ([B,N,C] bf16), K = wk*x ([B,N,C]),
// V = wv*x ([B,C,N]).  All D-fragments oriented so stores are bf16x4.
// ---------------------------------------------------------------------------
__global__ __launch_bounds__(256) void qkv_k(
    const float* __restrict__ x,
    const float* __restrict__ wq, const float* __restrict__ wk, const float* __restrict__ wv,
    const float* __restrict__ w1, const float* __restrict__ w2,
    u16* __restrict__ Qg, u16* __restrict__ Kg, u16* __restrict__ Vg,
    u16* __restrict__ w1b, u16* __restrict__ w2b)
{
    const int b = blockIdx.y, nt = blockIdx.x, t = threadIdx.x;
    const int lane = t & 63, wave = t >> 6, g = lane >> 4, r16 = lane & 15;
    __shared__ __align__(16) u16 xT[128 * 64];   // swizzled bf16 [n_local][c]
    const int n0 = nt * 128;

    // weight fragments: W[(r16+16*tile)][8g+e+32kc] — usable as A (i=o) or B (j=o)
    bf16x8 wqf[4][2], wkf[4][2], wvf[4][2];
#pragma unroll
    for (int jt = 0; jt < 4; ++jt)
#pragma unroll
        for (int kc = 0; kc < 2; ++kc) {
            const int ro = (r16 + 16 * jt) * 64 + 8 * g + 32 * kc;
            wqf[jt][kc] = cvt8(wq + ro, 0.125f * LOG2E);  // fold 1/sqrt(C) and log2(e)
            wkf[jt][kc] = cvt8(wk + ro, 1.0f);
            wvf[jt][kc] = cvt8(wv + ro, 1.0f);
        }

    { // stage x tile transposed (n-major) + swizzled, as bf16
        int c = t >> 5;
        const int nn = (t & 31) * 4;
#pragma unroll
        for (int pass = 0; pass < 8; ++pass, c += 8) {
            f32x4 v = *(const f32x4*)&x[(size_t)(b * 64 + c) * 2048 + n0 + nn];
#pragma unroll
            for (int j = 0; j < 4; ++j)
                xT[swz(nn + j, 2 * c) >> 1] = __builtin_bit_cast(u16, (__bf16)v[j]);
        }
    }
    if (b == 0 && nt == 0) {
        for (int i = t; i < H_ * C_; i += 256) w1b[i] = __builtin_bit_cast(u16, (__bf16)w1[i]);
        for (int i = t; i < C_ * H_; i += 256) w2b[i] = __builtin_bit_cast(u16, (__bf16)w2[i]);
    }
    __syncthreads();

#pragma unroll
    for (int p = 0; p < 2; ++p) {
        const int nt16 = wave * 2 + p;
        bf16x8 xa[2];  // x^T tile frag: A (i=n) or B (j=n)
#pragma unroll
        for (int kc = 0; kc < 2; ++kc)
            xa[kc] = *(const bf16x8*)&xT[swz(nt16 * 16 + r16, 16 * g + 64 * kc) >> 1];
        // Q,K: D[o][n] -> row o = 16jt+4g+r, col n = r16 -> vector store along o
#pragma unroll
        for (int jt = 0; jt < 4; ++jt) {
            f32x4 aq = {0.f, 0.f, 0.f, 0.f}, ak = {0.f, 0.f, 0.f, 0.f};
            aq = MFMA(wqf[jt][0], xa[0], aq); aq = MFMA(wqf[jt][1], xa[1], aq);
            ak = MFMA(wkf[jt][0], xa[0], ak); ak = MFMA(wkf[jt][1], xa[1], ak);
            bf16x4 qk, kk;
#pragma unroll
            for (int r = 0; r < 4; ++r) { qk[r] = (__bf16)aq[r]; kk[r] = (__bf16)ak[r]; }
            const size_t ro = (size_t)(b * 2048 + n0 + nt16 * 16 + r16) * 64 + 16 * jt + 4 * g;
            *(bf16x4*)&Qg[ro] = qk;
            *(bf16x4*)&Kg[ro] = kk;
        }
        // V: D[n][o] -> row n = nt16*16+4g+r, col o = 16it+r16 -> vector store along n
#pragma unroll
        for (int it = 0; it < 4; ++it) {
            f32x4 av = {0.f, 0.f, 0.f, 0.f};
            av = MFMA(xa[0], wvf[it][0], av);
            av = MFMA(xa[1], wvf[it][1], av);
            bf16x4 vk;
#pragma unroll
            for (int r = 0; r < 4; ++r) vk[r] = (__bf16)av[r];
            *(bf16x4*)&Vg[(size_t)(b * 64 + 16 * it + r16) * 2048 + n0 + nt16 * 16 + 4 * g] = vk;
        }
    }
}

// ---------------------------------------------------------------------------
// Kernel 2: flash attention.  1024 blocks (XCD-pinned per batch), 4 waves,
// 16 q rows per wave.  K/V double-buffered in LDS via global_load_lds w=16.
// S^T = mfma(K,Q): lane owns q-row (r16) -> softmax = 15 fmax + 2 shuffles.
// O^T = mfma(V^T, P^T); P via per-wave LDS roundtrip (b32 writes, 2-way max).
// Epilogue: y = x + O/l  plus fused per-block BN1 partial sums.
// ---------------------------------------------------------------------------
__global__ __launch_bounds__(256) void attn_k(
    const u16* __restrict__ Qg, const u16* __restrict__ Kg, const u16* __restrict__ Vg,
    const float* __restrict__ x, float* __restrict__ y,
    float* __restrict__ ps, float* __restrict__ pq)
{
    const int t = threadIdx.x;
    const int lane = t & 63, wave = t >> 6, g = lane >> 4, r16 = lane & 15;
    // XCD-pinning swizzle: linear%8 = XCD (round-robin dispatch); give each XCD
    // 4 whole batches so its L2 only holds 4x512KB of K/V.
    const int L = blockIdx.y * gridDim.x + blockIdx.x;   // 0..1023
    const int xcd = L & 7, slot = L >> 3;
    const int b = xcd + 8 * (slot >> 5);
    const int qt = slot & 31;

    __shared__ __align__(16) u16 Kt[2][64 * 64];   // swizzled [m][c], dbuf (16KB)
    __shared__ __align__(16) u16 Vt[2][64 * 64];   // swizzled [c][m], dbuf (16KB)
    __shared__ __align__(16) u16 Pl[4][16 * 64];   // per-wave P [q][m]    (8KB)

    const int n0 = qt * 64 + wave * 16;
    const int n = n0 + r16;
    const u16* qrow = Qg + (size_t)(b * 2048 + n) * 64 + 8 * g;
    const bf16x8 qf0 = *(const bf16x8*)qrow;
    const bf16x8 qf1 = *(const bf16x8*)(qrow + 32);

    // preload residual x[c][n] for epilogue (hides cold HBM read under loop)
    f32x4 xr[4];
#pragma unroll
    for (int ct = 0; ct < 4; ++ct)
#pragma unroll
        for (int r = 0; r < 4; ++r)
            xr[ct][r] = x[(size_t)(b * 64 + 16 * ct + 4 * g + r) * 2048 + n];

    f32x4 acc[4];
#pragma unroll
    for (int ct = 0; ct < 4; ++ct) acc[ct] = (f32x4){0.f, 0.f, 0.f, 0.f};
    float m = -1e30f, lp = 0.f;

    // staging: linear LDS dest (wave-uniform base + lane*16), inverse-swizzled
    // global source so swizzled ds_read patterns see the right data.
    const char* Kgb = (const char*)Kg + (size_t)b * 2048 * 128;
    const char* Vgb = (const char*)Vg + (size_t)b * 64 * 4096;
    const int srcxor = (((lane & 7) ^ (lane >> 3)) << 4);
    const int rowb = wave * 16 + (lane >> 3);   // row index base (+8j per instr)

    auto stage = [&](int kv, int buf) {
#pragma unroll
        for (int j = 0; j < 2; ++j) {
            const char* gk = Kgb + (size_t)(kv + rowb + 8 * j) * 128 + srcxor;
            const char* gv = Vgb + (size_t)(rowb + 8 * j) * 4096 + kv * 2 + srcxor;
            char* lk = (char*)&Kt[buf][0] + (wave * 2 + j) * 1024;
            char* lv = (char*)&Vt[buf][0] + (wave * 2 + j) * 1024;
            __builtin_amdgcn_global_load_lds(
                (const __attribute__((address_space(1))) void*)gk,
                (__attribute__((address_space(3))) void*)lk, 16, 0, 0);
            __builtin_amdgcn_global_load_lds(
                (const __attribute__((address_space(1))) void*)gv,
                (__attribute__((address_space(3))) void*)lv, 16, 0, 0);
        }
    };

    stage(0, 0);

#pragma unroll 1
    for (int kvt = 0; kvt < 32; ++kvt) {
        __syncthreads();                     // buf[kvt&1] ready (vmcnt drained here)
        if (kvt < 31) stage((kvt + 1) * 64, (kvt + 1) & 1);
        const char* Kc = (const char*)&Kt[kvt & 1][0];
        const char* Vc = (const char*)&Vt[kvt & 1][0];

        bf16x8 kf[4][2];
#pragma unroll
        for (int it = 0; it < 4; ++it)
#pragma unroll
            for (int kc = 0; kc < 2; ++kc)
                kf[it][kc] = *(const bf16x8*)(Kc + swz(16 * it + r16, 16 * g + 64 * kc));
        f32x4 s[4];
#pragma unroll
        for (int it = 0; it < 4; ++it) {
            f32x4 a = {0.f, 0.f, 0.f, 0.f};
            a = MFMA(kf[it][0], qf0, a);
            a = MFMA(kf[it][1], qf1, a);
            s[it] = a;    // S^T[m=16it+4g+r][q=r16], log2 domain
        }
        // V A-frags — issue before softmax to hide LDS latency
        bf16x8 vf[4][2];
#pragma unroll
        for (int ct = 0; ct < 4; ++ct)
#pragma unroll
            for (int kc = 0; kc < 2; ++kc)
                vf[ct][kc] = *(const bf16x8*)(Vc + swz(16 * ct + r16, 16 * g + 64 * kc));

        // row max: 15 local + 2 shuffles
        float pm = s[0][0];
#pragma unroll
        for (int it = 0; it < 4; ++it)
#pragma unroll
            for (int r = 0; r < 4; ++r) pm = fmaxf(pm, s[it][r]);
        pm = fmaxf(pm, __shfl_xor(pm, 16, 64));
        pm = fmaxf(pm, __shfl_xor(pm, 32, 64));
        // defer-max (T13): rescale only when max grows by >8 (log2 domain)
        if (!__all(pm <= m + 8.f)) {
            const float mn = fmaxf(m, pm);
            const float al = exp2f(m - mn);
            m = mn;
            lp *= al;
#pragma unroll
            for (int ct = 0; ct < 4; ++ct)
#pragma unroll
                for (int r = 0; r < 4; ++r) acc[ct][r] *= al;
        }
        // P = exp2(S - m); partial row sum; volatile b32 pair writes (2-way max)
        float ls = 0.f;
#pragma unroll
        for (int it = 0; it < 4; ++it) {
            u16 pb[4];
#pragma unroll
            for (int r = 0; r < 4; ++r) {
                const float pv = exp2f(s[it][r] - m);
                ls += pv;
                pb[r] = __builtin_bit_cast(u16, (__bf16)pv);
            }
            const u32 lo = (u32)pb[0] | ((u32)pb[1] << 16);
            const u32 hi = (u32)pb[2] | ((u32)pb[3] << 16);
            volatile u32* w0 = (volatile u32*)((char*)Pl[wave] + swz(r16, 32 * it + 8 * g));
            w0[0] = lo;
            w0[1] = hi;
        }
        lp += ls;
        // P^T B-frags: P[q=r16][m=8g+e+32kc]
        const bf16x8 pf0 = *(const bf16x8*)((const char*)Pl[wave] + swz(r16, 16 * g));
        const bf16x8 pf1 = *(const bf16x8*)((const char*)Pl[wave] + swz(r16, 16 * g + 64));
#pragma unroll
        for (int ct = 0; ct < 4; ++ct) {
            acc[ct] = MFMA(vf[ct][0], pf0, acc[ct]);
            acc[ct] = MFMA(vf[ct][1], pf1, acc[ct]);
        }
    }

    // epilogue: normalize, add residual, store y[B,N,C], fused BN1 partials
    float l = lp;
    l += __shfl_xor(l, 16, 64);
    l += __shfl_xor(l, 32, 64);
    const float inv = 1.0f / l;
    float sv[4][4], qv[4][4];
#pragma unroll
    for (int ct = 0; ct < 4; ++ct) {
        f32x4 o;
#pragma unroll
        for (int r = 0; r < 4; ++r) {
            o[r] = acc[ct][r] * inv + xr[ct][r];
            sv[ct][r] = o[r];
            qv[ct][r] = o[r] * o[r];
        }
        *(f32x4*)&y[(size_t)(b * 2048 + n) * 64 + 16 * ct + 4 * g] = o;
    }
    // reduce stats over the wave's 16 q rows (across r16)
#pragma unroll
    for (int d = 1; d <= 8; d <<= 1)
#pragma unroll
        for (int ct = 0; ct < 4; ++ct)
#pragma unroll
            for (int r = 0; r < 4; ++r) {
                sv[ct][r] += __shfl_xor(sv[ct][r], d, 64);
                qv[ct][r] += __shfl_xor(qv[ct][r], d, 64);
            }
    __syncthreads();                       // all waves done with Pl
    float* sb = (float*)&Pl[0][0];         // [0..255]=sum, [256..511]=sumsq
    if (r16 == 0) {
#pragma unroll
        for (int ct = 0; ct < 4; ++ct)
#pragma unroll
            for (int r = 0; r < 4; ++r) {
                const int c = 16 * ct + 4 * g + r;
                sb[wave * 64 + c] = sv[ct][r];
                sb[256 + wave * 64 + c] = qv[ct][r];
            }
    }
    __syncthreads();
    if (t < 64) {
        ps[L * 64 + t] = sb[t] + sb[64 + t] + sb[128 + t] + sb[192 + t];
        pq[L * 64 + t] = sb[256 + t] + sb[320 + t] + sb[384 + t] + sb[448 + t];
    }
}

// ---------------------------------------------------------------------------
// finalize: sum nblk per-block partials -> per-channel scale/shift
// ---------------------------------------------------------------------------
__global__ __launch_bounds__(256) void finalize_k(
    const float* __restrict__ psum, const float* __restrict__ psq,
    const float* __restrict__ gamma, const float* __restrict__ beta,
    float* __restrict__ ss, int nblk)
{
    const int t = threadIdx.x, c = t & 63, g = t >> 6;
    float s = 0.f, q = 0.f;
    for (int bl = g; bl < nblk; bl += 4) { s += psum[bl * 64 + c]; q += psq[bl * 64 + c]; }
    __shared__ float ls[4][64], lq[4][64];
    ls[g][c] = s; lq[g][c] = q;
    __syncthreads();
    if (t < 64) {
        s = ls[0][t] + ls[1][t] + ls[2][t] + ls[3][t];
        q = lq[0][t] + lq[1][t] + lq[2][t] + lq[3][t];
        const float mean = s * (1.0f / 65536.0f);
        const float var  = q * (1.0f / 65536.0f) - mean * mean;
        const float sc   = rsqrtf(var + 1e-5f) * gamma[t];
        ss[t] = sc;
        ss[64 + t] = beta[t] - mean * sc;
    }
}

// ---------------------------------------------------------------------------
// Kernel: h = BN1(y); ff = W2 * lrelu(W1 * h); z = h + ff   ([B,N,C] f32)
// plus fused BN2 partial sums.
// ---------------------------------------------------------------------------
__global__ __launch_bounds__(256) void ff_k(
    const float* __restrict__ y, const float* __restrict__ ss1,
    const u16* __restrict__ w1b, const u16* __restrict__ w2b,
    float* __restrict__ z, float* __restrict__ ps, float* __restrict__ pq)
{
    const int b = blockIdx.y, nt = blockIdx.x, t = threadIdx.x;
    const int lane = t & 63, wave = t >> 6, g = lane >> 4, r16 = lane & 15;
    const int L = blockIdx.y * gridDim.x + blockIdx.x;
    __shared__ __align__(16) u16 hT[64 * 64];       // swizzled bf16 [n][c]
    __shared__ __align__(16) float hf[64 * 68];     // f32 [n][c], pad 68
    __shared__ __align__(16) u16 pb[4][16 * 128];   // per-wave swizzled [n][h]
    __shared__ float sc1[64], sh1[64];
    if (t < 64) { sc1[t] = ss1[t]; sh1[t] = ss1[64 + t]; }
    __syncthreads();
    const int n0 = nt * 64;
    {
        const int i = t >> 2, c0 = (t & 3) * 16;
        u16 hb[16] __attribute__((aligned(16)));
#pragma unroll
        for (int q4 = 0; q4 < 4; ++q4) {
            const int c = c0 + 4 * q4;
            f32x4 v = *(const f32x4*)&y[(size_t)(b * 2048 + n0 + i) * 64 + c];
            f32x4 hv;
#pragma unroll
            for (int j = 0; j < 4; ++j) hv[j] = v[j] * sc1[c + j] + sh1[c + j];
            *(f32x4*)&hf[i * 68 + c] = hv;
#pragma unroll
            for (int j = 0; j < 4; ++j) hb[4 * q4 + j] = __builtin_bit_cast(u16, (__bf16)hv[j]);
        }
        *(uint4*)&hT[swz(i, 2 * c0) >> 1]      = *(const uint4*)&hb[0];
        *(uint4*)&hT[swz(i, 2 * c0 + 16) >> 1] = *(const uint4*)&hb[8];
    }
    __syncthreads();

    bf16x8 ha[2];
#pragma unroll
    for (int kc = 0; kc < 2; ++kc)
        ha[kc] = *(const bf16x8*)&hT[swz(wave * 16 + r16, 16 * g + 64 * kc) >> 1];
    // ff1 = lrelu(W1 * h), written transposed to pb
#pragma unroll
    for (int it = 0; it < 8; ++it) {
        f32x4 a = {0.f, 0.f, 0.f, 0.f};
#pragma unroll
        for (int kc = 0; kc < 2; ++kc) {
            bf16x8 w1f = *(const bf16x8*)&w1b[(r16 + 16 * it) * 64 + 8 * g + 32 * kc];
            a = MFMA(w1f, ha[kc], a);
        }
        u16x4 pk;
#pragma unroll
        for (int r = 0; r < 4; ++r) {
            const float rv = a[r] >= 0.f ? a[r] : 0.2f * a[r];
            pk[r] = __builtin_bit_cast(u16, (__bf16)rv);
        }
        *(u16x4*)&pb[wave][swz256(r16, 2 * (16 * it + 4 * g)) >> 1] = pk;
    }
    // ff2: D[c][n] (A=w2f, B=pa) -> vector store along c; z = h + ff2
    bf16x8 pa[4];
#pragma unroll
    for (int kc = 0; kc < 4; ++kc)
        pa[kc] = *(const bf16x8*)&pb[wave][swz256(r16, 16 * g + 64 * kc) >> 1];
    const int nl = wave * 16 + r16;
    float sv[4][4], qv[4][4];
#pragma unroll
    for (int jt = 0; jt < 4; ++jt) {
        f32x4 a = {0.f, 0.f, 0.f, 0.f};
#pragma unroll
        for (int kc = 0; kc < 4; ++kc) {
            bf16x8 w2f = *(const bf16x8*)&w2b[(r16 + 16 * jt) * 128 + 8 * g + 32 * kc];
            a = MFMA(w2f, pa[kc], a);
        }
        f32x4 h4 = *(const f32x4*)&hf[nl * 68 + 16 * jt + 4 * g];
#pragma unroll
        for (int r = 0; r < 4; ++r) {
            a[r] += h4[r];
            sv[jt][r] = a[r];
            qv[jt][r] = a[r] * a[r];
        }
        *(f32x4*)&z[(size_t)(b * 2048 + n0 + nl) * 64 + 16 * jt + 4 * g] = a;
    }
    // fused BN2 partials: reduce over the wave's 16 rows (across r16)
#pragma unroll
    for (int d = 1; d <= 8; d <<= 1)
#pragma unroll
        for (int jt = 0; jt < 4; ++jt)
#pragma unroll
            for (int r = 0; r < 4; ++r) {
                sv[jt][r] += __shfl_xor(sv[jt][r], d, 64);
                qv[jt][r] += __shfl_xor(qv[jt][r], d, 64);
            }
    __syncthreads();                       // all waves done with pb
    float* sb = (float*)&pb[0][0];
    if (r16 == 0) {
#pragma unroll
        for (int jt = 0; jt < 4; ++jt)
#pragma unroll
            for (int r = 0; r < 4; ++r) {
                const int c = 16 * jt + 4 * g + r;
                sb[wave * 64 + c] = sv[jt][r];
                sb[256 + wave * 64 + c] = qv[jt][r];
            }
    }
    __syncthreads();
    if (t < 64) {
        ps[L * 64 + t] = sb[t] + sb[64 + t] + sb[128 + t] + sb[192 + t];
        pq[L * 64 + t] = sb[256 + t] + sb[320 + t] + sb[384 + t] + sb[448 + t];
    }
}

// ---------------------------------------------------------------------------
// Kernel: out[B,C,N] = BN2(z[B,N,C])  (LDS transpose)
// ---------------------------------------------------------------------------
__global__ __launch_bounds__(256) void bnout_k(
    const float* __restrict__ z, const float* __restrict__ ss2, float* __restrict__ out)
{
    const int b = blockIdx.y, nt = blockIdx.x, t = threadIdx.x;
    __shared__ float tile[64 * 65];
    __shared__ float sc2[64], sh2[64];
    if (t < 64) { sc2[t] = ss2[t]; sh2[t] = ss2[64 + t]; }
    __syncthreads();
    const int n0 = nt * 64;
    {
        const int i = t >> 2, c0 = (t & 3) * 16;
#pragma unroll
        for (int q4 = 0; q4 < 4; ++q4) {
            const int c = c0 + 4 * q4;
            f32x4 v = *(const f32x4*)&z[(size_t)(b * 2048 + n0 + i) * 64 + c];
#pragma unroll
            for (int j = 0; j < 4; ++j)
                tile[(i)*65 + c + j] = v[j] * sc2[c + j] + sh2[c + j];
        }
    }
    __syncthreads();
    {
        const int c = t >> 2, j0 = (t & 3) * 16;
#pragma unroll
        for (int q4 = 0; q4 < 4; ++q4) {
            f32x4 ov;
#pragma unroll
            for (int j = 0; j < 4; ++j)
                ov[j] = tile[(j0 + 4 * q4 + j) * 65 + c];
            *(f32x4*)&out[(size_t)(b * 64 + c) * 2048 + n0 + j0 + 4 * q4] = ov;
        }
    }
}

extern "C" void kernel_launch(void* const* d_in, const int* in_sizes, int n_in,
                              void* d_out, int out_size, void* d_ws, size_t ws_size,
                              hipStream_t stream)
{
    const float* x   = (const float*)d_in[0];
    const float* wq  = (const float*)d_in[1];
    const float* wk  = (const float*)d_in[2];
    const float* wv  = (const float*)d_in[3];
    const float* w1  = (const float*)d_in[4];
    const float* w2  = (const float*)d_in[5];
    const float* g1  = (const float*)d_in[6];
    const float* be1 = (const float*)d_in[7];
    const float* g2  = (const float*)d_in[8];
    const float* be2 = (const float*)d_in[9];
    float* out = (float*)d_out;

    char* w = (char*)d_ws;
    u16* Qg = (u16*)w;   w += (size_t)B_ * N_ * C_ * 2;
    u16* Kg = (u16*)w;   w += (size_t)B_ * N_ * C_ * 2;
    u16* Vg = (u16*)w;   w += (size_t)B_ * N_ * C_ * 2;
    float* y = (float*)w; w += (size_t)B_ * N_ * C_ * 4;
    float* z = (float*)w; w += (size_t)B_ * N_ * C_ * 4;
    u16* w1b = (u16*)w;  w += (size_t)H_ * C_ * 2;
    u16* w2b = (u16*)w;  w += (size_t)C_ * H_ * 2;
    float* ps1 = (float*)w; w += 1024 * 64 * 4;
    float* pq1 = (float*)w; w += 1024 * 64 * 4;
    float* ps2 = (float*)w; w += 1024 * 64 * 4;
    float* pq2 = (float*)w; w += 1024 * 64 * 4;
    float* ss1 = (float*)w; w += 128 * 4;
    float* ss2 = (float*)w; w += 128 * 4;

    const dim3 blk(256);
    hipLaunchKernelGGL(qkv_k,   dim3(16, 32), blk, 0, stream, x, wq, wk, wv, w1, w2, Qg, Kg, Vg, w1b, w2b);
    hipLaunchKernelGGL(attn_k,  dim3(32, 32), blk, 0, stream, Qg, Kg, Vg, x, y, ps1, pq1);
    hipLaunchKernelGGL(finalize_k, dim3(1),   blk, 0, stream, ps1, pq1, g1, be1, ss1, 1024);
    hipLaunchKernelGGL(ff_k,    dim3(32, 32), blk, 0, stream, y, ss1, w1b, w2b, z, ps2, pq2);
    hipLaunchKernelGGL(finalize_k, dim3(1),   blk, 0, stream, ps2, pq2, g2, be2, ss2, 1024);
    hipLaunchKernelGGL(bnout_k, dim3(32, 32), blk, 0, stream, z, ss2, out);
}

// Round 5
// 152.945 us; speedup vs baseline: 1.9908x; 1.9908x over previous
//
#include <hip/hip_runtime.h>

#define B_ 32
#define C_ 64
#define N_ 2048
#define H_ 128

typedef unsigned short u16;
typedef unsigned int u32;
typedef float f32x4 __attribute__((ext_vector_type(4)));
typedef __bf16 bf16x8 __attribute__((ext_vector_type(8)));
typedef __bf16 bf16x4 __attribute__((ext_vector_type(4)));
typedef unsigned short u16x4 __attribute__((ext_vector_type(4)));

#define MFMA(a, b, c) __builtin_amdgcn_mfma_f32_16x16x32_bf16(a, b, c, 0, 0, 0)
#define LOG2E 1.44269504088896f

// XOR swizzle for 128-byte-stride LDS rows (bf16 [*][64]); returns BYTE offset.
__device__ __forceinline__ int swz(int row, int cb) { return row * 128 + (cb ^ ((row & 7) << 4)); }
// same for 256-byte-stride rows (bf16 [*][128])
__device__ __forceinline__ int swz256(int row, int cb) { return row * 256 + (cb ^ ((row & 7) << 4)); }

__device__ __forceinline__ bf16x8 cvt8(const float* p, float s) {
    f32x4 a = *(const f32x4*)p, b = *(const f32x4*)(p + 4);
    bf16x8 o;
    o[0] = (__bf16)(a[0] * s); o[1] = (__bf16)(a[1] * s);
    o[2] = (__bf16)(a[2] * s); o[3] = (__bf16)(a[3] * s);
    o[4] = (__bf16)(b[0] * s); o[5] = (__bf16)(b[1] * s);
    o[6] = (__bf16)(b[2] * s); o[7] = (__bf16)(b[3] * s);
    return o;
}

// ---------------------------------------------------------------------------
// Kernel 1: Q = (0.125*log2e)*wq*x ([B,N,C] bf16), K = wk*x ([B,N,C]),
// V = wv*x ([B,C,N]).  All D-fragments oriented so stores are bf16x4.
// ---------------------------------------------------------------------------
__global__ __launch_bounds__(256) void qkv_k(
    const float* __restrict__ x,
    const float* __restrict__ wq, const float* __restrict__ wk, const float* __restrict__ wv,
    const float* __restrict__ w1, const float* __restrict__ w2,
    u16* __restrict__ Qg, u16* __restrict__ Kg, u16* __restrict__ Vg,
    u16* __restrict__ w1b, u16* __restrict__ w2b)
{
    const int b = blockIdx.y, nt = blockIdx.x, t = threadIdx.x;
    const int lane = t & 63, wave = t >> 6, g = lane >> 4, r16 = lane & 15;
    __shared__ __align__(16) u16 xT[128 * 64];   // swizzled bf16 [n_local][c]
    const int n0 = nt * 128;

    // weight fragments: W[(r16+16*tile)][8g+e+32kc] — usable as A (i=o) or B (j=o)
    bf16x8 wqf[4][2], wkf[4][2], wvf[4][2];
#pragma unroll
    for (int jt = 0; jt < 4; ++jt)
#pragma unroll
        for (int kc = 0; kc < 2; ++kc) {
            const int ro = (r16 + 16 * jt) * 64 + 8 * g + 32 * kc;
            wqf[jt][kc] = cvt8(wq + ro, 0.125f * LOG2E);  // fold 1/sqrt(C) and log2(e)
            wkf[jt][kc] = cvt8(wk + ro, 1.0f);
            wvf[jt][kc] = cvt8(wv + ro, 1.0f);
        }

    { // stage x tile transposed (n-major) + swizzled, as bf16
        int c = t >> 5;
        const int nn = (t & 31) * 4;
#pragma unroll
        for (int pass = 0; pass < 8; ++pass, c += 8) {
            f32x4 v = *(const f32x4*)&x[(size_t)(b * 64 + c) * 2048 + n0 + nn];
#pragma unroll
            for (int j = 0; j < 4; ++j)
                xT[swz(nn + j, 2 * c) >> 1] = __builtin_bit_cast(u16, (__bf16)v[j]);
        }
    }
    if (b == 0 && nt == 0) {
        for (int i = t; i < H_ * C_; i += 256) w1b[i] = __builtin_bit_cast(u16, (__bf16)w1[i]);
        for (int i = t; i < C_ * H_; i += 256) w2b[i] = __builtin_bit_cast(u16, (__bf16)w2[i]);
    }
    __syncthreads();

#pragma unroll
    for (int p = 0; p < 2; ++p) {
        const int nt16 = wave * 2 + p;
        bf16x8 xa[2];  // x^T tile frag: A (i=n) or B (j=n)
#pragma unroll
        for (int kc = 0; kc < 2; ++kc)
            xa[kc] = *(const bf16x8*)&xT[swz(nt16 * 16 + r16, 16 * g + 64 * kc) >> 1];
        // Q,K: D[o][n] -> row o = 16jt+4g+r, col n = r16 -> vector store along o
#pragma unroll
        for (int jt = 0; jt < 4; ++jt) {
            f32x4 aq = {0.f, 0.f, 0.f, 0.f}, ak = {0.f, 0.f, 0.f, 0.f};
            aq = MFMA(wqf[jt][0], xa[0], aq); aq = MFMA(wqf[jt][1], xa[1], aq);
            ak = MFMA(wkf[jt][0], xa[0], ak); ak = MFMA(wkf[jt][1], xa[1], ak);
            bf16x4 qk, kk;
#pragma unroll
            for (int r = 0; r < 4; ++r) { qk[r] = (__bf16)aq[r]; kk[r] = (__bf16)ak[r]; }
            const size_t ro = (size_t)(b * 2048 + n0 + nt16 * 16 + r16) * 64 + 16 * jt + 4 * g;
            *(bf16x4*)&Qg[ro] = qk;
            *(bf16x4*)&Kg[ro] = kk;
        }
        // V: D[n][o] -> row n = nt16*16+4g+r, col o = 16it+r16 -> vector store along n
#pragma unroll
        for (int it = 0; it < 4; ++it) {
            f32x4 av = {0.f, 0.f, 0.f, 0.f};
            av = MFMA(xa[0], wvf[it][0], av);
            av = MFMA(xa[1], wvf[it][1], av);
            bf16x4 vk;
#pragma unroll
            for (int r = 0; r < 4; ++r) vk[r] = (__bf16)av[r];
            *(bf16x4*)&Vg[(size_t)(b * 64 + 16 * it + r16) * 2048 + n0 + nt16 * 16 + 4 * g] = vk;
        }
    }
}

// ---------------------------------------------------------------------------
// Kernel 2: flash attention.  512 blocks, XCD-pinned (4 batches per XCD so
// each XCD's L2 holds only its 2 MB of K/V).  4 waves, 32 q rows per wave
// (2 groups of 16 sharing the K/V fragments).  K/V double-buffered in LDS via
// global_load_lds w=16 with pre-swizzled source.
// S^T = mfma(K,Q): lane owns q-row (r16) -> softmax = 15 fmax + 2 shuffles.
// O^T = mfma(V^T, P^T); P via per-wave LDS roundtrip.
// Epilogue: y = x + O/l  plus fused per-block BN1 partial sums.
// ---------------------------------------------------------------------------
__global__ __launch_bounds__(256) void attn_k(
    const u16* __restrict__ Qg, const u16* __restrict__ Kg, const u16* __restrict__ Vg,
    const float* __restrict__ x, float* __restrict__ y,
    float* __restrict__ ps, float* __restrict__ pq)
{
    const int t = threadIdx.x;
    const int lane = t & 63, wave = t >> 6, g = lane >> 4, r16 = lane & 15;
    // XCD-pinning: linear%8 = XCD (round-robin dispatch); 4 whole batches/XCD.
    const int L = blockIdx.x;              // 0..511
    const int xcd = L & 7, slot = L >> 3;  // slot 0..63
    const int b = xcd * 4 + (slot >> 4);
    const int qt = slot & 15;

    __shared__ __align__(16) u16 Kt[2][64 * 64];     // swizzled [m][c], dbuf (16KB)
    __shared__ __align__(16) u16 Vt[2][64 * 64];     // swizzled [c][m], dbuf (16KB)
    __shared__ __align__(16) u16 Pl[4][2][16 * 64];  // per-wave/group P [q][m] (16KB)

    const int n0 = qt * 128 + wave * 32;
    bf16x8 qf[2][2];
#pragma unroll
    for (int u = 0; u < 2; ++u) {
        const u16* qrow = Qg + (size_t)(b * 2048 + n0 + 16 * u + r16) * 64 + 8 * g;
        qf[u][0] = *(const bf16x8*)qrow;
        qf[u][1] = *(const bf16x8*)(qrow + 32);
    }
    // preload residual x[c][n] for epilogue (hides cold HBM read under loop)
    f32x4 xr[2][4];
#pragma unroll
    for (int u = 0; u < 2; ++u)
#pragma unroll
        for (int ct = 0; ct < 4; ++ct)
#pragma unroll
            for (int r = 0; r < 4; ++r)
                xr[u][ct][r] = x[(size_t)(b * 64 + 16 * ct + 4 * g + r) * 2048 + n0 + 16 * u + r16];

    f32x4 acc[2][4];
    float m[2] = {-1e30f, -1e30f}, lp[2] = {0.f, 0.f};
#pragma unroll
    for (int u = 0; u < 2; ++u)
#pragma unroll
        for (int ct = 0; ct < 4; ++ct) acc[u][ct] = (f32x4){0.f, 0.f, 0.f, 0.f};

    // staging: linear LDS dest (wave-uniform base + lane*16), inverse-swizzled
    // global source so swizzled ds_read patterns see the right data.
    const char* Kgb = (const char*)Kg + (size_t)b * 2048 * 128;
    const char* Vgb = (const char*)Vg + (size_t)b * 64 * 4096;
    const int srcxor = (((lane & 7) ^ (lane >> 3)) << 4);
    const int rowb = wave * 16 + (lane >> 3);   // row index base (+8j per instr)

    auto stage = [&](int kv, int buf) {
#pragma unroll
        for (int j = 0; j < 2; ++j) {
            const char* gk = Kgb + (size_t)(kv + rowb + 8 * j) * 128 + srcxor;
            const char* gv = Vgb + (size_t)(rowb + 8 * j) * 4096 + kv * 2 + srcxor;
            char* lk = (char*)&Kt[buf][0] + (wave * 2 + j) * 1024;
            char* lv = (char*)&Vt[buf][0] + (wave * 2 + j) * 1024;
            __builtin_amdgcn_global_load_lds(
                (const __attribute__((address_space(1))) void*)gk,
                (__attribute__((address_space(3))) void*)lk, 16, 0, 0);
            __builtin_amdgcn_global_load_lds(
                (const __attribute__((address_space(1))) void*)gv,
                (__attribute__((address_space(3))) void*)lv, 16, 0, 0);
        }
    };

    stage(0, 0);

#pragma unroll 1
    for (int kvt = 0; kvt < 32; ++kvt) {
        __syncthreads();                     // buf[kvt&1] ready (vmcnt drained here)
        if (kvt < 31) stage((kvt + 1) * 64, (kvt + 1) & 1);
        const char* Kc = (const char*)&Kt[kvt & 1][0];
        const char* Vc = (const char*)&Vt[kvt & 1][0];

        // K A-frags, then QK^T for both q-groups (kf shared)
        bf16x8 kf[4][2];
#pragma unroll
        for (int it = 0; it < 4; ++it)
#pragma unroll
            for (int kc = 0; kc < 2; ++kc)
                kf[it][kc] = *(const bf16x8*)(Kc + swz(16 * it + r16, 16 * g + 64 * kc));
        f32x4 s[2][4];
#pragma unroll
        for (int it = 0; it < 4; ++it) {
            f32x4 a0 = {0.f, 0.f, 0.f, 0.f}, a1 = {0.f, 0.f, 0.f, 0.f};
            a0 = MFMA(kf[it][0], qf[0][0], a0); a0 = MFMA(kf[it][1], qf[0][1], a0);
            a1 = MFMA(kf[it][0], qf[1][0], a1); a1 = MFMA(kf[it][1], qf[1][1], a1);
            s[0][it] = a0; s[1][it] = a1;    // S^T[m=16it+4g+r][q=r16], log2 domain
        }
        // V A-frags (shared by both groups) — issue before softmax
        bf16x8 vf[4][2];
#pragma unroll
        for (int ct = 0; ct < 4; ++ct)
#pragma unroll
            for (int kc = 0; kc < 2; ++kc)
                vf[ct][kc] = *(const bf16x8*)(Vc + swz(16 * ct + r16, 16 * g + 64 * kc));

#pragma unroll
        for (int u = 0; u < 2; ++u) {
            // row max: 15 local + 2 shuffles
            float pm = s[u][0][0];
#pragma unroll
            for (int it = 0; it < 4; ++it)
#pragma unroll
                for (int r = 0; r < 4; ++r) pm = fmaxf(pm, s[u][it][r]);
            pm = fmaxf(pm, __shfl_xor(pm, 16, 64));
            pm = fmaxf(pm, __shfl_xor(pm, 32, 64));
            // defer-max (T13): rescale only when max grows by >8 (log2 domain)
            if (!__all(pm <= m[u] + 8.f)) {
                const float mn = fmaxf(m[u], pm);
                const float al = exp2f(m[u] - mn);
                m[u] = mn;
                lp[u] *= al;
#pragma unroll
                for (int ct = 0; ct < 4; ++ct)
#pragma unroll
                    for (int r = 0; r < 4; ++r) acc[u][ct][r] *= al;
            }
            // P = exp2(S - m); partial row sum; bf16x4 -> per-wave LDS
            float ls = 0.f;
#pragma unroll
            for (int it = 0; it < 4; ++it) {
                bf16x4 pk;
#pragma unroll
                for (int r = 0; r < 4; ++r) {
                    const float pv = exp2f(s[u][it][r] - m[u]);
                    ls += pv;
                    pk[r] = (__bf16)pv;
                }
                *(bf16x4*)((char*)Pl[wave][u] + swz(r16, 32 * it + 8 * g)) = pk;
            }
            lp[u] += ls;
            // P^T B-frags: P[q=r16][m=8g+e+32kc]
            const bf16x8 pf0 = *(const bf16x8*)((const char*)Pl[wave][u] + swz(r16, 16 * g));
            const bf16x8 pf1 = *(const bf16x8*)((const char*)Pl[wave][u] + swz(r16, 16 * g + 64));
#pragma unroll
            for (int ct = 0; ct < 4; ++ct) {
                acc[u][ct] = MFMA(vf[ct][0], pf0, acc[u][ct]);
                acc[u][ct] = MFMA(vf[ct][1], pf1, acc[u][ct]);
            }
        }
    }

    // epilogue: normalize, add residual, store y[B,N,C]; fused BN1 partials
    float sv[4][4], qv[4][4];
#pragma unroll
    for (int ct = 0; ct < 4; ++ct)
#pragma unroll
        for (int r = 0; r < 4; ++r) { sv[ct][r] = 0.f; qv[ct][r] = 0.f; }
#pragma unroll
    for (int u = 0; u < 2; ++u) {
        float l = lp[u];
        l += __shfl_xor(l, 16, 64);
        l += __shfl_xor(l, 32, 64);
        const float inv = 1.0f / l;
        const int n = n0 + 16 * u + r16;
#pragma unroll
        for (int ct = 0; ct < 4; ++ct) {
            f32x4 o;
#pragma unroll
            for (int r = 0; r < 4; ++r) {
                o[r] = acc[u][ct][r] * inv + xr[u][ct][r];
                sv[ct][r] += o[r];
                qv[ct][r] += o[r] * o[r];
            }
            *(f32x4*)&y[(size_t)(b * 2048 + n) * 64 + 16 * ct + 4 * g] = o;
        }
    }
    // reduce stats over the wave's 32 q rows (across r16)
#pragma unroll
    for (int d = 1; d <= 8; d <<= 1)
#pragma unroll
        for (int ct = 0; ct < 4; ++ct)
#pragma unroll
            for (int r = 0; r < 4; ++r) {
                sv[ct][r] += __shfl_xor(sv[ct][r], d, 64);
                qv[ct][r] += __shfl_xor(qv[ct][r], d, 64);
            }
    __syncthreads();                       // all waves done with Pl
    float* sb = (float*)&Pl[0][0][0];      // [0..255]=sum, [256..511]=sumsq
    if (r16 == 0) {
#pragma unroll
        for (int ct = 0; ct < 4; ++ct)
#pragma unroll
            for (int r = 0; r < 4; ++r) {
                const int c = 16 * ct + 4 * g + r;
                sb[wave * 64 + c] = sv[ct][r];
                sb[256 + wave * 64 + c] = qv[ct][r];
            }
    }
    __syncthreads();
    if (t < 64) {
        ps[L * 64 + t] = sb[t] + sb[64 + t] + sb[128 + t] + sb[192 + t];
        pq[L * 64 + t] = sb[256 + t] + sb[320 + t] + sb[384 + t] + sb[448 + t];
    }
}

// ---------------------------------------------------------------------------
// finalize: 64 blocks (one channel each) sum nblk partials -> scale/shift
// ---------------------------------------------------------------------------
__global__ __launch_bounds__(256) void finalize_k(
    const float* __restrict__ psum, const float* __restrict__ psq,
    const float* __restrict__ gamma, const float* __restrict__ beta,
    float* __restrict__ ss, int nblk)
{
    const int c = blockIdx.x, t = threadIdx.x;
    const int lane = t & 63, wave = t >> 6;
    float s = 0.f, q = 0.f;
    for (int bl = t; bl < nblk; bl += 256) {
        s += psum[bl * 64 + c];
        q += psq[bl * 64 + c];
    }
#pragma unroll
    for (int d = 1; d <= 32; d <<= 1) {
        s += __shfl_xor(s, d, 64);
        q += __shfl_xor(q, d, 64);
    }
    __shared__ float ls[4], lq[4];
    if (lane == 0) { ls[wave] = s; lq[wave] = q; }
    __syncthreads();
    if (t == 0) {
        s = ls[0] + ls[1] + ls[2] + ls[3];
        q = lq[0] + lq[1] + lq[2] + lq[3];
        const float mean = s * (1.0f / 65536.0f);
        const float var  = q * (1.0f / 65536.0f) - mean * mean;
        const float sc   = rsqrtf(var + 1e-5f) * gamma[c];
        ss[c] = sc;
        ss[64 + c] = beta[c] - mean * sc;
    }
}

// ---------------------------------------------------------------------------
// Kernel: h = BN1(y); ff = W2 * lrelu(W1 * h); z = h + ff   ([B,N,C] f32)
// plus fused BN2 partial sums.
// ---------------------------------------------------------------------------
__global__ __launch_bounds__(256) void ff_k(
    const float* __restrict__ y, const float* __restrict__ ss1,
    const u16* __restrict__ w1b, const u16* __restrict__ w2b,
    float* __restrict__ z, float* __restrict__ ps, float* __restrict__ pq)
{
    const int b = blockIdx.y, nt = blockIdx.x, t = threadIdx.x;
    const int lane = t & 63, wave = t >> 6, g = lane >> 4, r16 = lane & 15;
    const int L = blockIdx.y * gridDim.x + blockIdx.x;
    __shared__ __align__(16) u16 hT[64 * 64];       // swizzled bf16 [n][c]
    __shared__ __align__(16) float hf[64 * 68];     // f32 [n][c], pad 68
    __shared__ __align__(16) u16 pb[4][16 * 128];   // per-wave swizzled [n][h]
    __shared__ float sc1[64], sh1[64];
    if (t < 64) { sc1[t] = ss1[t]; sh1[t] = ss1[64 + t]; }
    __syncthreads();
    const int n0 = nt * 64;
    {
        const int i = t >> 2, c0 = (t & 3) * 16;
        u16 hb[16] __attribute__((aligned(16)));
#pragma unroll
        for (int q4 = 0; q4 < 4; ++q4) {
            const int c = c0 + 4 * q4;
            f32x4 v = *(const f32x4*)&y[(size_t)(b * 2048 + n0 + i) * 64 + c];
            f32x4 hv;
#pragma unroll
            for (int j = 0; j < 4; ++j) hv[j] = v[j] * sc1[c + j] + sh1[c + j];
            *(f32x4*)&hf[i * 68 + c] = hv;
#pragma unroll
            for (int j = 0; j < 4; ++j) hb[4 * q4 + j] = __builtin_bit_cast(u16, (__bf16)hv[j]);
        }
        *(uint4*)&hT[swz(i, 2 * c0) >> 1]      = *(const uint4*)&hb[0];
        *(uint4*)&hT[swz(i, 2 * c0 + 16) >> 1] = *(const uint4*)&hb[8];
    }
    __syncthreads();

    bf16x8 ha[2];
#pragma unroll
    for (int kc = 0; kc < 2; ++kc)
        ha[kc] = *(const bf16x8*)&hT[swz(wave * 16 + r16, 16 * g + 64 * kc) >> 1];
    // ff1 = lrelu(W1 * h), written transposed to pb
#pragma unroll
    for (int it = 0; it < 8; ++it) {
        f32x4 a = {0.f, 0.f, 0.f, 0.f};
#pragma unroll
        for (int kc = 0; kc < 2; ++kc) {
            bf16x8 w1f = *(const bf16x8*)&w1b[(r16 + 16 * it) * 64 + 8 * g + 32 * kc];
            a = MFMA(w1f, ha[kc], a);
        }
        u16x4 pk;
#pragma unroll
        for (int r = 0; r < 4; ++r) {
            const float rv = a[r] >= 0.f ? a[r] : 0.2f * a[r];
            pk[r] = __builtin_bit_cast(u16, (__bf16)rv);
        }
        *(u16x4*)&pb[wave][swz256(r16, 2 * (16 * it + 4 * g)) >> 1] = pk;
    }
    // ff2: D[c][n] (A=w2f, B=pa) -> vector store along c; z = h + ff2
    bf16x8 pa[4];
#pragma unroll
    for (int kc = 0; kc < 4; ++kc)
        pa[kc] = *(const bf16x8*)&pb[wave][swz256(r16, 16 * g + 64 * kc) >> 1];
    const int nl = wave * 16 + r16;
    float sv[4][4], qv[4][4];
#pragma unroll
    for (int jt = 0; jt < 4; ++jt) {
        f32x4 a = {0.f, 0.f, 0.f, 0.f};
#pragma unroll
        for (int kc = 0; kc < 4; ++kc) {
            bf16x8 w2f = *(const bf16x8*)&w2b[(r16 + 16 * jt) * 128 + 8 * g + 32 * kc];
            a = MFMA(w2f, pa[kc], a);
        }
        f32x4 h4 = *(const f32x4*)&hf[nl * 68 + 16 * jt + 4 * g];
#pragma unroll
        for (int r = 0; r < 4; ++r) {
            a[r] += h4[r];
            sv[jt][r] = a[r];
            qv[jt][r] = a[r] * a[r];
        }
        *(f32x4*)&z[(size_t)(b * 2048 + n0 + nl) * 64 + 16 * jt + 4 * g] = a;
    }
    // fused BN2 partials: reduce over the wave's 16 rows (across r16)
#pragma unroll
    for (int d = 1; d <= 8; d <<= 1)
#pragma unroll
        for (int jt = 0; jt < 4; ++jt)
#pragma unroll
            for (int r = 0; r < 4; ++r) {
                sv[jt][r] += __shfl_xor(sv[jt][r], d, 64);
                qv[jt][r] += __shfl_xor(qv[jt][r], d, 64);
            }
    __syncthreads();                       // all waves done with pb
    float* sb = (float*)&pb[0][0];
    if (r16 == 0) {
#pragma unroll
        for (int jt = 0; jt < 4; ++jt)
#pragma unroll
            for (int r = 0; r < 4; ++r) {
                const int c = 16 * jt + 4 * g + r;
                sb[wave * 64 + c] = sv[jt][r];
                sb[256 + wave * 64 + c] = qv[jt][r];
            }
    }
    __syncthreads();
    if (t < 64) {
        ps[L * 64 + t] = sb[t] + sb[64 + t] + sb[128 + t] + sb[192 + t];
        pq[L * 64 + t] = sb[256 + t] + sb[320 + t] + sb[384 + t] + sb[448 + t];
    }
}

// ---------------------------------------------------------------------------
// Kernel: out[B,C,N] = BN2(z[B,N,C])  (LDS transpose)
// ---------------------------------------------------------------------------
__global__ __launch_bounds__(256) void bnout_k(
    const float* __restrict__ z, const float* __restrict__ ss2, float* __restrict__ out)
{
    const int b = blockIdx.y, nt = blockIdx.x, t = threadIdx.x;
    __shared__ float tile[64 * 65];
    __shared__ float sc2[64], sh2[64];
    if (t < 64) { sc2[t] = ss2[t]; sh2[t] = ss2[64 + t]; }
    __syncthreads();
    const int n0 = nt * 64;
    {
        const int i = t >> 2, c0 = (t & 3) * 16;
#pragma unroll
        for (int q4 = 0; q4 < 4; ++q4) {
            const int c = c0 + 4 * q4;
            f32x4 v = *(const f32x4*)&z[(size_t)(b * 2048 + n0 + i) * 64 + c];
#pragma unroll
            for (int j = 0; j < 4; ++j)
                tile[(i)*65 + c + j] = v[j] * sc2[c + j] + sh2[c + j];
        }
    }
    __syncthreads();
    {
        const int c = t >> 2, j0 = (t & 3) * 16;
#pragma unroll
        for (int q4 = 0; q4 < 4; ++q4) {
            f32x4 ov;
#pragma unroll
            for (int j = 0; j < 4; ++j)
                ov[j] = tile[(j0 + 4 * q4 + j) * 65 + c];
            *(f32x4*)&out[(size_t)(b * 64 + c) * 2048 + n0 + j0 + 4 * q4] = ov;
        }
    }
}

extern "C" void kernel_launch(void* const* d_in, const int* in_sizes, int n_in,
                              void* d_out, int out_size, void* d_ws, size_t ws_size,
                              hipStream_t stream)
{
    const float* x   = (const float*)d_in[0];
    const float* wq  = (const float*)d_in[1];
    const float* wk  = (const float*)d_in[2];
    const float* wv  = (const float*)d_in[3];
    const float* w1  = (const float*)d_in[4];
    const float* w2  = (const float*)d_in[5];
    const float* g1  = (const float*)d_in[6];
    const float* be1 = (const float*)d_in[7];
    const float* g2  = (const float*)d_in[8];
    const float* be2 = (const float*)d_in[9];
    float* out = (float*)d_out;

    char* w = (char*)d_ws;
    u16* Qg = (u16*)w;   w += (size_t)B_ * N_ * C_ * 2;
    u16* Kg = (u16*)w;   w += (size_t)B_ * N_ * C_ * 2;
    u16* Vg = (u16*)w;   w += (size_t)B_ * N_ * C_ * 2;
    float* y = (float*)w; w += (size_t)B_ * N_ * C_ * 4;
    float* z = (float*)w; w += (size_t)B_ * N_ * C_ * 4;
    u16* w1b = (u16*)w;  w += (size_t)H_ * C_ * 2;
    u16* w2b = (u16*)w;  w += (size_t)C_ * H_ * 2;
    float* ps1 = (float*)w; w += 1024 * 64 * 4;
    float* pq1 = (float*)w; w += 1024 * 64 * 4;
    float* ps2 = (float*)w; w += 1024 * 64 * 4;
    float* pq2 = (float*)w; w += 1024 * 64 * 4;
    float* ss1 = (float*)w; w += 128 * 4;
    float* ss2 = (float*)w; w += 128 * 4;

    const dim3 blk(256);
    hipLaunchKernelGGL(qkv_k,   dim3(16, 32), blk, 0, stream, x, wq, wk, wv, w1, w2, Qg, Kg, Vg, w1b, w2b);
    hipLaunchKernelGGL(attn_k,  dim3(512),    blk, 0, stream, Qg, Kg, Vg, x, y, ps1, pq1);
    hipLaunchKernelGGL(finalize_k, dim3(64),  blk, 0, stream, ps1, pq1, g1, be1, ss1, 512);
    hipLaunchKernelGGL(ff_k,    dim3(32, 32), blk, 0, stream, y, ss1, w1b, w2b, z, ps2, pq2);
    hipLaunchKernelGGL(finalize_k, dim3(64),  blk, 0, stream, ps2, pq2, g2, be2, ss2, 1024);
    hipLaunchKernelGGL(bnout_k, dim3(32, 32), blk, 0, stream, z, ss2, out);
}